// Round 13
// baseline (525.990 us; speedup 1.0000x reference)
//
#include <hip/hip_runtime.h>
#include <math.h>

#define NN 6000
#define EE 100000
#define ELL (EE + NN)   // edges + self loops for GAT
#define CAP 64          // bucket-CSR capacity per node (max deg ~45 << 64)

// packed CSR entry: src (13b) | rel<<13 | self<<14
#define PK_SRC(p)  ((p) & 0x1FFF)
#define PK_REL(p)  (((p) >> 13) & 1)
#define PK_SELF(p) ((p) & 0x4000)

typedef __attribute__((ext_vector_type(8))) short frag8;           // 8 bf16 (4 VGPR)
typedef __attribute__((ext_vector_type(4))) float f32x4;
typedef __attribute__((ext_vector_type(8))) unsigned short u16x8;  // 16B of bf16

__device__ __forceinline__ unsigned short f2bf(float f){
  unsigned u = __float_as_uint(f);
  unsigned r = u + 0x7FFFu + ((u >> 16) & 1u);   // round-to-nearest-even
  return (unsigned short)(r >> 16);
}
__device__ __forceinline__ float bf2f(unsigned short s){
  return __uint_as_float(((unsigned)s) << 16);
}

// ---- prep (PROBE x reps on idempotent part): CSR fill once (atomics), then
// W016/Wcat/Bt16/gwa repeated with runtime-zero offset (anti-LICM). ----
__global__ void k_pdc(const int* __restrict__ ei, const int* __restrict__ et,
                      int* __restrict__ cursor, int* __restrict__ pks,
                      const float* __restrict__ basis0, const float* __restrict__ comp0,
                      const float* __restrict__ b1,const float* __restrict__ c1,const float* __restrict__ r1,
                      const float* __restrict__ b2,const float* __restrict__ c2,const float* __restrict__ r2,
                      const float* __restrict__ b3,const float* __restrict__ c3,const float* __restrict__ r3,
                      const float* __restrict__ w1,
                      const float* __restrict__ gw, const float* __restrict__ a_src,
                      const float* __restrict__ a_dst,
                      unsigned short* __restrict__ W016, float* __restrict__ Wcat,
                      unsigned short* __restrict__ Bt16, float* __restrict__ gwa,
                      const int* __restrict__ zbuf, int reps){
  int t0 = blockIdx.x*256 + threadIdx.x;
  int z0 = zbuf[0], z1 = zbuf[1];
  for (int rep = 0; rep < reps; rep++){
    int zz = ((rep & 1) ? z1 : z0) * rep;       // == 0 at runtime
    if (rep == 0 && t0 < ELL){
      int d, pk;
      if (t0 < EE){
        d = ei[EE+t0];
        pk = ei[t0] | (et[t0] << 13);
      } else {
        d = t0 - EE; pk = d | 0x4000;
      }
      int pos = atomicAdd(&cursor[d], 1);
      pks[d*CAP + pos] = pk;
    }
    int t0r = t0 + zz;                          // == t0 at runtime
    if (t0r < 2*NN*32){
      int r = t0r / (NN*32);
      int no = t0r - r*(NN*32);
      float acc = 0.f;
      #pragma unroll
      for (int b=0;b<4;b++) acc += comp0[r*4+b] * basis0[b*(NN*32)+no];
      W016[t0r] = f2bf(acc);
    } else {
      int tw = t0r - 2*NN*32;
      if (tw < 24576){
        const float *bb,*cc,*rr; int I,O; int t = tw;
        if (tw < 6144)        { bb=b1;cc=c1;rr=r1;I=32;O=64; }
        else if (tw < 18432)  { bb=b2;cc=c2;rr=r2;I=64;O=64; t -= 6144; }
        else                  { bb=b3;cc=c3;rr=r3;I=64;O=32; t -= 18432; }
        int C = 3*O;
        int i = t / C; int col = t - i*C;
        float v;
        if (col < O) v = rr[i*O + col];
        else {
          int r = (col - O) / O; int o = col - O - r*O;
          v = 0.f;
          #pragma unroll
          for (int b=0;b<4;b++) v += cc[r*4+b]*bb[(b*I+i)*O + o];
        }
        Wcat[tw] = v;
      } else {
        int tb = tw - 24576;           // Bt16: [n][k], n in [0,256), k in [0,512)
        if (tb < 256*512){
          int n = tb >> 9, k = tb & 511;
          float v = (n < 128) ? w1[k*128 + n] : w1[(512+k)*128 + (n-128)];
          Bt16[tb] = f2bf(v);
        } else {
          int ti = tb - 256*512;       // gwa: 4096 threads = 64 waves, 1/output
          if (ti < 64*64){
            int w = ti >> 6, lane = ti & 63;
            const float* av = (w < 32) ? a_src : a_dst;
            int i = w & 31;
            float s = 0.f;
            #pragma unroll
            for (int q=0;q<8;q++){
              int k = lane + q*64;
              s += gw[i*512 + k]*av[k];
            }
            #pragma unroll
            for (int off=32;off>0;off>>=1) s += __shfl_xor(s, off, 64);
            if (lane == 0) gwa[w] = s;
          }
        }
      }
    }
  }
}

// ---- F1: wave-per-node gather (x=I) + nodemm 32x192 -> H16 [N,192] ----
// (R11 config: no min-waves bound — R12's (512,8) forced spills, VGPR 32.)
__global__ void __launch_bounds__(512) k_f1(
    const unsigned short* __restrict__ W016, const float* __restrict__ root,
    const float* __restrict__ rbias0,
    const int* __restrict__ degc, const int* __restrict__ pks,
    const float* __restrict__ Wc, unsigned short* __restrict__ Hout){
  __shared__ float sx[8*32];
  int n0 = blockIdx.x*8;
  int t = threadIdx.x, nl = t>>6, lane = t&63, o = lane&31, h = lane>>5;
  int n = n0 + nl;
  int r0 = n*CAP, deg = degc[n];
  int pk = (lane < deg) ? pks[r0 + lane] : 0x4000;   // full CSR row in registers
  float a0 = 0.f, a1 = 0.f, c0 = 0.f, c1 = 0.f;
  int trips = (deg + 1) >> 1;                        // edges e = 2*jj + h
  for (int jj = 0; jj < trips; jj += 4){
    int pA = __shfl(pk, 2*jj + h, 64);
    int pB = __shfl(pk, min(2*jj + 2 + h, 63), 64);
    int pC = __shfl(pk, min(2*jj + 4 + h, 63), 64);
    int pD = __shfl(pk, min(2*jj + 6 + h, 63), 64);
    float vA = bf2f(W016[(PK_REL(pA)*NN + PK_SRC(pA))*32 + o]);
    float vB = bf2f(W016[(PK_REL(pB)*NN + PK_SRC(pB))*32 + o]);
    float vC = bf2f(W016[(PK_REL(pC)*NN + PK_SRC(pC))*32 + o]);
    float vD = bf2f(W016[(PK_REL(pD)*NN + PK_SRC(pD))*32 + o]);
    if (!PK_SELF(pA)){ if (PK_REL(pA)==0){ a0 += vA; c0 += 1.f; } else { a1 += vA; c1 += 1.f; } }
    if (!PK_SELF(pB)){ if (PK_REL(pB)==0){ a0 += vB; c0 += 1.f; } else { a1 += vB; c1 += 1.f; } }
    if (!PK_SELF(pC)){ if (PK_REL(pC)==0){ a0 += vC; c0 += 1.f; } else { a1 += vC; c1 += 1.f; } }
    if (!PK_SELF(pD)){ if (PK_REL(pD)==0){ a0 += vD; c0 += 1.f; } else { a1 += vD; c1 += 1.f; } }
  }
  a0 += __shfl_xor(a0, 32, 64); a1 += __shfl_xor(a1, 32, 64);
  c0 += __shfl_xor(c0, 32, 64); c1 += __shfl_xor(c1, 32, 64);
  float v = tanhf(root[n*32+o] + rbias0[o] + a0/fmaxf(c0,1.f) + a1/fmaxf(c1,1.f));
  if (h == 0) sx[nl*32+o] = v;
  __syncthreads();
  if (t < 384){
    int col = t % 192, grp = t / 192;        // grp 0/1 -> nodes grp*4 .. +3
    float acc[4] = {0,0,0,0};
    for (int i=0;i<32;i++){
      float w = Wc[i*192 + col];
      #pragma unroll
      for (int tt=0;tt<4;tt++) acc[tt] += sx[(grp*4+tt)*32+i]*w;
    }
    #pragma unroll
    for (int tt=0;tt<4;tt++) Hout[(n0+grp*4+tt)*192 + col] = f2bf(acc[tt]);
  }
}

// ---- F2: wave-per-node ragg<64> (Hin stride 192) + nodemm 64x192, 8 nodes/blk ----
__global__ void __launch_bounds__(512) k_f2(
    const unsigned short* __restrict__ Hin, const float* __restrict__ rbias,
    const int* __restrict__ degc, const int* __restrict__ pks,
    const float* __restrict__ Wc, unsigned short* __restrict__ Hout){
  __shared__ float sx[8*64];
  int n0 = blockIdx.x*8;
  int t = threadIdx.x, nl = t>>6, lane = t&63, o0 = (lane&31)*2, h = lane>>5;
  int n = n0 + nl;
  int r0 = n*CAP, deg = degc[n];
  int pk = (lane < deg) ? pks[r0 + lane] : 0x4000;
  float a00=0.f, a01=0.f, a10=0.f, a11=0.f, c0=0.f, c1=0.f;
  int trips = (deg + 1) >> 1;
  for (int jj = 0; jj < trips; jj += 4){
    int pA = __shfl(pk, 2*jj + h, 64);
    int pB = __shfl(pk, min(2*jj + 2 + h, 63), 64);
    int pC = __shfl(pk, min(2*jj + 4 + h, 63), 64);
    int pD = __shfl(pk, min(2*jj + 6 + h, 63), 64);
    unsigned hvA = *(const unsigned*)&Hin[PK_SRC(pA)*192 + 64 + PK_REL(pA)*64 + o0];
    unsigned hvB = *(const unsigned*)&Hin[PK_SRC(pB)*192 + 64 + PK_REL(pB)*64 + o0];
    unsigned hvC = *(const unsigned*)&Hin[PK_SRC(pC)*192 + 64 + PK_REL(pC)*64 + o0];
    unsigned hvD = *(const unsigned*)&Hin[PK_SRC(pD)*192 + 64 + PK_REL(pD)*64 + o0];
    if (!PK_SELF(pA)){
      float v0 = bf2f((unsigned short)(hvA & 0xFFFF));
      float v1 = bf2f((unsigned short)(hvA >> 16));
      if (PK_REL(pA)==0){ a00 += v0; a01 += v1; c0 += 1.f; } else { a10 += v0; a11 += v1; c1 += 1.f; }
    }
    if (!PK_SELF(pB)){
      float v0 = bf2f((unsigned short)(hvB & 0xFFFF));
      float v1 = bf2f((unsigned short)(hvB >> 16));
      if (PK_REL(pB)==0){ a00 += v0; a01 += v1; c0 += 1.f; } else { a10 += v0; a11 += v1; c1 += 1.f; }
    }
    if (!PK_SELF(pC)){
      float v0 = bf2f((unsigned short)(hvC & 0xFFFF));
      float v1 = bf2f((unsigned short)(hvC >> 16));
      if (PK_REL(pC)==0){ a00 += v0; a01 += v1; c0 += 1.f; } else { a10 += v0; a11 += v1; c1 += 1.f; }
    }
    if (!PK_SELF(pD)){
      float v0 = bf2f((unsigned short)(hvD & 0xFFFF));
      float v1 = bf2f((unsigned short)(hvD >> 16));
      if (PK_REL(pD)==0){ a00 += v0; a01 += v1; c0 += 1.f; } else { a10 += v0; a11 += v1; c1 += 1.f; }
    }
  }
  a00 += __shfl_xor(a00, 32, 64); a01 += __shfl_xor(a01, 32, 64);
  a10 += __shfl_xor(a10, 32, 64); a11 += __shfl_xor(a11, 32, 64);
  c0  += __shfl_xor(c0, 32, 64);  c1  += __shfl_xor(c1, 32, 64);
  float i0 = 1.f/fmaxf(c0,1.f), i1 = 1.f/fmaxf(c1,1.f);
  if (h == 0){
    sx[nl*64+o0]   = tanhf(bf2f(Hin[n*192+o0])   + rbias[o0]   + a00*i0 + a10*i1);
    sx[nl*64+o0+1] = tanhf(bf2f(Hin[n*192+o0+1]) + rbias[o0+1] + a01*i0 + a11*i1);
  }
  __syncthreads();
  if (t < 384){
    int col = t % 192, grp = t / 192;        // grp 0/1 -> nodes grp*4 .. +3
    float acc[4] = {0,0,0,0};
    for (int i=0;i<64;i++){
      float w = Wc[i*192 + col];
      #pragma unroll
      for (int tt=0;tt<4;tt++) acc[tt] += sx[(grp*4+tt)*64+i]*w;
    }
    #pragma unroll
    for (int tt=0;tt<4;tt++) Hout[(n0+grp*4+tt)*192 + col] = f2bf(acc[tt]);
  }
}

// ---- F3: wave-per-node ragg<64> (Hin stride 192) + nodemm 64x96, 8 nodes/blk ----
__global__ void __launch_bounds__(512) k_f3(
    const unsigned short* __restrict__ Hin, const float* __restrict__ rbias,
    const int* __restrict__ degc, const int* __restrict__ pks,
    const float* __restrict__ Wc, unsigned short* __restrict__ Hout){
  __shared__ float sx[8*64];
  int n0 = blockIdx.x*8;
  int t = threadIdx.x, nl = t>>6, lane = t&63, o0 = (lane&31)*2, h = lane>>5;
  int n = n0 + nl;
  int r0 = n*CAP, deg = degc[n];
  int pk = (lane < deg) ? pks[r0 + lane] : 0x4000;
  float a00=0.f, a01=0.f, a10=0.f, a11=0.f, c0=0.f, c1=0.f;
  int trips = (deg + 1) >> 1;
  for (int jj = 0; jj < trips; jj += 4){
    int pA = __shfl(pk, 2*jj + h, 64);
    int pB = __shfl(pk, min(2*jj + 2 + h, 63), 64);
    int pC = __shfl(pk, min(2*jj + 4 + h, 63), 64);
    int pD = __shfl(pk, min(2*jj + 6 + h, 63), 64);
    unsigned hvA = *(const unsigned*)&Hin[PK_SRC(pA)*192 + 64 + PK_REL(pA)*64 + o0];
    unsigned hvB = *(const unsigned*)&Hin[PK_SRC(pB)*192 + 64 + PK_REL(pB)*64 + o0];
    unsigned hvC = *(const unsigned*)&Hin[PK_SRC(pC)*192 + 64 + PK_REL(pC)*64 + o0];
    unsigned hvD = *(const unsigned*)&Hin[PK_SRC(pD)*192 + 64 + PK_REL(pD)*64 + o0];
    if (!PK_SELF(pA)){
      float v0 = bf2f((unsigned short)(hvA & 0xFFFF));
      float v1 = bf2f((unsigned short)(hvA >> 16));
      if (PK_REL(pA)==0){ a00 += v0; a01 += v1; c0 += 1.f; } else { a10 += v0; a11 += v1; c1 += 1.f; }
    }
    if (!PK_SELF(pB)){
      float v0 = bf2f((unsigned short)(hvB & 0xFFFF));
      float v1 = bf2f((unsigned short)(hvB >> 16));
      if (PK_REL(pB)==0){ a00 += v0; a01 += v1; c0 += 1.f; } else { a10 += v0; a11 += v1; c1 += 1.f; }
    }
    if (!PK_SELF(pC)){
      float v0 = bf2f((unsigned short)(hvC & 0xFFFF));
      float v1 = bf2f((unsigned short)(hvC >> 16));
      if (PK_REL(pC)==0){ a00 += v0; a01 += v1; c0 += 1.f; } else { a10 += v0; a11 += v1; c1 += 1.f; }
    }
    if (!PK_SELF(pD)){
      float v0 = bf2f((unsigned short)(hvD & 0xFFFF));
      float v1 = bf2f((unsigned short)(hvD >> 16));
      if (PK_REL(pD)==0){ a00 += v0; a01 += v1; c0 += 1.f; } else { a10 += v0; a11 += v1; c1 += 1.f; }
    }
  }
  a00 += __shfl_xor(a00, 32, 64); a01 += __shfl_xor(a01, 32, 64);
  a10 += __shfl_xor(a10, 32, 64); a11 += __shfl_xor(a11, 32, 64);
  c0  += __shfl_xor(c0, 32, 64);  c1  += __shfl_xor(c1, 32, 64);
  float i0 = 1.f/fmaxf(c0,1.f), i1 = 1.f/fmaxf(c1,1.f);
  if (h == 0){
    sx[nl*64+o0]   = tanhf(bf2f(Hin[n*192+o0])   + rbias[o0]   + a00*i0 + a10*i1);
    sx[nl*64+o0+1] = tanhf(bf2f(Hin[n*192+o0+1]) + rbias[o0+1] + a01*i0 + a11*i1);
  }
  __syncthreads();
  if (t < 384){
    int c = t % 96, grp = t / 96;            // grp 0..3 -> nodes grp*2 .. +1
    float acc[2] = {0,0};
    for (int i=0;i<64;i++){
      float w = Wc[i*96 + c];
      #pragma unroll
      for (int tt=0;tt<2;tt++) acc[tt] += sx[(grp*2+tt)*64+i]*w;
    }
    #pragma unroll
    for (int tt=0;tt<2;tt++) Hout[(n0+grp*2+tt)*96 + c] = f2bf(acc[tt]);
  }
}

// ---- F4': wave-per-node ragg<32> (stride 96) -> X4 bf16 [N,32] + GAT scores ----
__global__ void __launch_bounds__(256) k_f4(
    const unsigned short* __restrict__ Hin, const float* __restrict__ rbias,
    const int* __restrict__ degc, const int* __restrict__ pks,
    const float* __restrict__ gwa,
    unsigned short* __restrict__ X4, float* __restrict__ asv, float* __restrict__ adv){
  int n0 = blockIdx.x*4;
  int t = threadIdx.x, nl = t>>6, lane = t&63, o = lane&31, h = lane>>5;
  int n = n0 + nl;
  int r0 = n*CAP, deg = degc[n];
  int pk = (lane < deg) ? pks[r0 + lane] : 0x4000;
  float a0=0.f, a1=0.f, c0=0.f, c1=0.f;
  int trips = (deg + 1) >> 1;
  for (int jj = 0; jj < trips; jj += 4){
    int pA = __shfl(pk, 2*jj + h, 64);
    int pB = __shfl(pk, min(2*jj + 2 + h, 63), 64);
    int pC = __shfl(pk, min(2*jj + 4 + h, 63), 64);
    int pD = __shfl(pk, min(2*jj + 6 + h, 63), 64);
    float vA = bf2f(Hin[PK_SRC(pA)*96 + 32 + PK_REL(pA)*32 + o]);
    float vB = bf2f(Hin[PK_SRC(pB)*96 + 32 + PK_REL(pB)*32 + o]);
    float vC = bf2f(Hin[PK_SRC(pC)*96 + 32 + PK_REL(pC)*32 + o]);
    float vD = bf2f(Hin[PK_SRC(pD)*96 + 32 + PK_REL(pD)*32 + o]);
    if (!PK_SELF(pA)){ if (PK_REL(pA)==0){ a0 += vA; c0 += 1.f; } else { a1 += vA; c1 += 1.f; } }
    if (!PK_SELF(pB)){ if (PK_REL(pB)==0){ a0 += vB; c0 += 1.f; } else { a1 += vB; c1 += 1.f; } }
    if (!PK_SELF(pC)){ if (PK_REL(pC)==0){ a0 += vC; c0 += 1.f; } else { a1 += vC; c1 += 1.f; } }
    if (!PK_SELF(pD)){ if (PK_REL(pD)==0){ a0 += vD; c0 += 1.f; } else { a1 += vD; c1 += 1.f; } }
  }
  a0 += __shfl_xor(a0, 32, 64); a1 += __shfl_xor(a1, 32, 64);
  c0 += __shfl_xor(c0, 32, 64); c1 += __shfl_xor(c1, 32, 64);
  float v = tanhf(bf2f(Hin[n*96+o]) + rbias[o] + a0/fmaxf(c0,1.f) + a1/fmaxf(c1,1.f));
  if (h == 0) X4[n*32 + o] = f2bf(v);
  // scores: half 0 reduces v*gwa_src, half 1 reduces v*gwa_dst (both have v)
  float s = v * gwa[h*32 + o];
  #pragma unroll
  for (int off=16;off>0;off>>=1) s += __shfl_xor(s, off, 64);  // stays in-half
  if (lane == 0)       asv[n] = s;
  else if (lane == 32) adv[n] = s;
}

// ---- GS2: GAT softmax + aggregate on X4, 1 wave per node (6000 waves) ----
__global__ void __launch_bounds__(256) k_gs2(
    const int* __restrict__ degc, const int* __restrict__ pks,
    const float* __restrict__ asv, const float* __restrict__ adv,
    const unsigned short* __restrict__ X4, float* __restrict__ xagg){
  int t = threadIdx.x, w = t>>6, lane = t&63;
  int n = blockIdx.x*4 + w;
  int r0 = n*CAP, deg = degc[n];
  float advn = adv[n];
  int pk  = (lane < deg) ? pks[r0 + lane] : -1;
  int src = (pk >= 0) ? PK_SRC(pk) : 0;
  float aa = -1e30f;
  if (pk >= 0){
    float a = asv[src] + advn;
    aa = (a >= 0.f) ? a : 0.2f*a;
  }
  float m = aa;
  #pragma unroll
  for (int off=32;off>0;off>>=1) m = fmaxf(m, __shfl_xor(m,off,64));
  float ex = (pk >= 0) ? expf(aa - m) : 0.f;
  float se = ex;
  #pragma unroll
  for (int off=32;off>0;off>>=1) se += __shfl_xor(se,off,64);
  float inv = 1.f / fmaxf(se, 1e-16f);
  int c = lane & 31, h = lane >> 5;
  float acc = 0.f;
  int trips = (deg + 1) >> 1;
  for (int jj = 0; jj < trips; jj += 4){
    float cfA = __shfl(ex, 2*jj + h, 64);
    int   svA = __shfl(src, 2*jj + h, 64);
    float cfB = __shfl(ex, min(2*jj + 2 + h, 63), 64);
    int   svB = __shfl(src, min(2*jj + 2 + h, 63), 64);
    float cfC = __shfl(ex, min(2*jj + 4 + h, 63), 64);
    int   svC = __shfl(src, min(2*jj + 4 + h, 63), 64);
    float cfD = __shfl(ex, min(2*jj + 6 + h, 63), 64);
    int   svD = __shfl(src, min(2*jj + 6 + h, 63), 64);
    float vA = bf2f(X4[svA*32 + c]);
    float vB = bf2f(X4[svB*32 + c]);
    float vC = bf2f(X4[svC*32 + c]);
    float vD = bf2f(X4[svD*32 + c]);
    acc += cfA * vA;
    acc += cfB * vB;
    acc += cfC * vC;
    acc += cfD * vD;
  }
  acc += __shfl_xor(acc, 32, 64);
  if (h == 0) xagg[n*32 + c] = acc * inv;
}

// ---- AB2 (PROBE x reps): gout = relu(xagg@gw+b) in LDS, MFMA vs Bt16 -> P16 ----
__global__ void __launch_bounds__(256) k_ab2(
    const float* __restrict__ xagg, const float* __restrict__ gw,
    const float* __restrict__ gat_b, const unsigned short* __restrict__ Bt16,
    unsigned short* __restrict__ P16, const int* __restrict__ zbuf, int reps){
  __shared__ float xa[16][33];
  __shared__ unsigned short go[16*520];
  int t = threadIdx.x, w = t>>6, lane = t&63;
  int n0 = blockIdx.x*16;
  int z0 = zbuf[0], z1 = zbuf[1];
  for (int rep = 0; rep < reps; rep++){
    int zz = ((rep & 1) ? z1 : z0) * rep;       // == 0 at runtime
    {
      int i0 = t, i1 = t + 256;
      xa[i0 >> 5][i0 & 31] = xagg[(n0+zz)*32 + i0];
      xa[i1 >> 5][i1 & 31] = xagg[(n0+zz)*32 + i1];
    }
    __syncthreads();
    {
      int c2 = t*2;
      float2 acc2[16];
      #pragma unroll
      for (int k=0;k<16;k++) acc2[k] = {0.f,0.f};
      for (int i=0;i<32;i++){
        const float2 g = *(const float2*)&gw[i*512 + c2 + zz];
        #pragma unroll
        for (int k=0;k<16;k++){
          float xv = xa[k][i];
          acc2[k].x += xv*g.x; acc2[k].y += xv*g.y;
        }
      }
      const float2 bv = *(const float2*)&gat_b[c2];
      #pragma unroll
      for (int k=0;k<16;k++){
        ushort2 ov;
        ov.x = f2bf(fmaxf(acc2[k].x + bv.x, 0.f));
        ov.y = f2bf(fmaxf(acc2[k].y + bv.y, 0.f));
        *(ushort2*)&go[k*520 + c2] = ov;
      }
    }
    __syncthreads();
    {
      int kq = (lane >> 4) * 8;
      const unsigned short* arow  = go + (lane & 15)*520 + kq;
      const unsigned short* bbase = Bt16 + (size_t)(w*64 + (lane & 15))*512 + kq + zz;
      f32x4 acc0 = {0,0,0,0}, acc1 = {0,0,0,0}, acc2 = {0,0,0,0}, acc3 = {0,0,0,0};
      for (int k = 0; k < 512; k += 32){
        frag8 a  = *(const frag8*)(arow + k);
        frag8 b0 = *(const frag8*)(bbase + k);
        frag8 b1 = *(const frag8*)(bbase + 16*512 + k);
        frag8 b2 = *(const frag8*)(bbase + 32*512 + k);
        frag8 b3 = *(const frag8*)(bbase + 48*512 + k);
        acc0 = __builtin_amdgcn_mfma_f32_16x16x32_bf16(a, b0, acc0, 0, 0, 0);
        acc1 = __builtin_amdgcn_mfma_f32_16x16x32_bf16(a, b1, acc1, 0, 0, 0);
        acc2 = __builtin_amdgcn_mfma_f32_16x16x32_bf16(a, b2, acc2, 0, 0, 0);
        acc3 = __builtin_amdgcn_mfma_f32_16x16x32_bf16(a, b3, acc3, 0, 0, 0);
      }
      int rowb = n0 + (lane >> 4)*4;
      int col  = w*64 + (lane & 15);
      #pragma unroll
      for (int i=0;i<4;i++){
        P16[(size_t)(rowb+i)*256 + col     ] = f2bf(acc0[i]);
        P16[(size_t)(rowb+i)*256 + col + 16] = f2bf(acc1[i]);
        P16[(size_t)(rowb+i)*256 + col + 32] = f2bf(acc2[i]);
        P16[(size_t)(rowb+i)*256 + col + 48] = f2bf(acc3[i]);
      }
    }
    __syncthreads();   // before next rep overwrites xa/go
  }
}

// ---- edge MLP head (PROBE x reps): 16 lanes/edge, bf16 P loads ----
__global__ void k_edge(const int* __restrict__ ei, const unsigned short* __restrict__ P16,
                       const float* __restrict__ b1,
                       const float* __restrict__ w2, const float* __restrict__ b2,
                       float* __restrict__ out,
                       const int* __restrict__ zbuf, int reps){
  int e = blockIdx.x*16 + (threadIdx.x >> 4);
  int l = threadIdx.x & 15;            // lane covers channels [l*8, l*8+8)
  if (e >= EE) return;
  int z0 = zbuf[0], z1 = zbuf[1];
  for (int rep = 0; rep < reps; rep++){
    int zz = ((rep & 1) ? z1 : z0) * rep;       // == 0 at runtime
    int s = ei[e + zz], d = ei[EE + e + zz];
    const u16x8 Av = *(const u16x8*)&P16[(size_t)s*256 + l*8];
    const u16x8 Bv = *(const u16x8*)&P16[(size_t)d*256 + 128 + l*8];
    const float4 b1a = *(const float4*)&b1[l*8];
    const float4 b1b = *(const float4*)&b1[l*8+4];
    const float4 w2a = *(const float4*)&w2[l*8];
    const float4 w2b = *(const float4*)&w2[l*8+4];
    float h0 = fmaxf(bf2f(Av[0])+bf2f(Bv[0])+b1a.x, 0.f);
    float h1 = fmaxf(bf2f(Av[1])+bf2f(Bv[1])+b1a.y, 0.f);
    float h2 = fmaxf(bf2f(Av[2])+bf2f(Bv[2])+b1a.z, 0.f);
    float h3 = fmaxf(bf2f(Av[3])+bf2f(Bv[3])+b1a.w, 0.f);
    float h4 = fmaxf(bf2f(Av[4])+bf2f(Bv[4])+b1b.x, 0.f);
    float h5 = fmaxf(bf2f(Av[5])+bf2f(Bv[5])+b1b.y, 0.f);
    float h6 = fmaxf(bf2f(Av[6])+bf2f(Bv[6])+b1b.z, 0.f);
    float h7 = fmaxf(bf2f(Av[7])+bf2f(Bv[7])+b1b.w, 0.f);
    float acc = h0*w2a.x + h1*w2a.y + h2*w2a.z + h3*w2a.w
              + h4*w2b.x + h5*w2b.y + h6*w2b.z + h7*w2b.w;
    #pragma unroll
    for (int m=8;m>0;m>>=1) acc += __shfl_xor(acc,m,64);
    if (l==0) out[e] = 1.f/(1.f + expf(-(acc + b2[0])));
  }
}

extern "C" void kernel_launch(void* const* d_in, const int* in_sizes, int n_in,
                              void* d_out, int out_size, void* d_ws, size_t ws_size,
                              hipStream_t stream){
  const float* basis0 = (const float*)d_in[0];
  const float* comp0  = (const float*)d_in[1];
  const float* root0  = (const float*)d_in[2];
  const float* rbias0 = (const float*)d_in[3];
  const float* basis1 = (const float*)d_in[4];
  const float* comp1  = (const float*)d_in[5];
  const float* root1  = (const float*)d_in[6];
  const float* rbias1 = (const float*)d_in[7];
  const float* basis2 = (const float*)d_in[8];
  const float* comp2  = (const float*)d_in[9];
  const float* root2  = (const float*)d_in[10];
  const float* rbias2 = (const float*)d_in[11];
  const float* basis3 = (const float*)d_in[12];
  const float* comp3  = (const float*)d_in[13];
  const float* root3  = (const float*)d_in[14];
  const float* rbias3 = (const float*)d_in[15];
  const float* gat_w = (const float*)d_in[16];
  const float* a_src = (const float*)d_in[17];
  const float* a_dst = (const float*)d_in[18];
  const float* gat_b = (const float*)d_in[19];
  const float* w1 = (const float*)d_in[20];
  const float* b1 = (const float*)d_in[21];
  const float* w2 = (const float*)d_in[22];
  const float* b2 = (const float*)d_in[23];
  const int* ei = (const int*)d_in[24];
  const int* et = (const int*)d_in[25];
  float* out = (float*)d_out;

  // workspace carve-up (16B-aligned sections)
  float* p = (float*)d_ws;
  int* zbuf   = (int*)p; p += 4;               // runtime zeros (anti-LICM probe)
  int* cursor = (int*)p; p += NN;              // doubles as degree after k_pdc
  int* pks    = (int*)p; p += NN*CAP;          // bucket CSR (64 slots/node)
  unsigned short* W016 = (unsigned short*)p; p += NN*32;       // 2*NN*32 bf16
  float* Wcat = p; p += 24576;
  unsigned short* Bt16 = (unsigned short*)p; p += 256*512/2;
  unsigned short* H16a = (unsigned short*)p; p += NN*96;       // NN*192 bf16
  unsigned short* H16b = (unsigned short*)p; p += NN*96;       // NN*192 bf16
  unsigned short* X4   = (unsigned short*)p; p += NN*16;       // NN*32 bf16
  float* gwa  = p; p += 64;                    // gw@a_src (32) + gw@a_dst (32)
  float* asv  = p; p += NN;
  float* adv  = p; p += NN;
  float* xagg = p; p += NN*32;                 // aggregated x (f32)
  unsigned short* P16 = (unsigned short*)p; p += NN*128;       // NN*256 bf16

  auto grid = [](long long n){ return dim3((unsigned)((n + 255)/256)); };
  const int REPS = 16;

  // ---- zero zbuf+cursor (adjacent) in one memset, then prep kernel (probe) ----
  hipMemsetAsync(zbuf, 0, (size_t)(4 + NN)*sizeof(int), stream);
  k_pdc<<<grid(2LL*NN*32 + 24576 + 256*512 + 64*64),256,0,stream>>>(ei, et, cursor, pks,
        basis0, comp0, basis1,comp1,root1, basis2,comp2,root2,
        basis3,comp3,root3, w1, gat_w, a_src, a_dst, W016, Wcat, Bt16, gwa,
        zbuf, REPS);

  // ---- RGCN stack: wave-per-node gathers; 8 nodes/block (R11 config) ----
  k_f1<<<dim3(NN/8),512,0,stream>>>(W016, root0, rbias0, cursor, pks, Wcat, H16a);
  k_f2<<<dim3(NN/8),512,0,stream>>>(H16a, rbias1, cursor, pks, Wcat + 6144, H16b);
  k_f3<<<dim3(NN/8),512,0,stream>>>(H16b, rbias2, cursor, pks, Wcat + 18432, H16a);
  k_f4<<<dim3(NN/4),256,0,stream>>>(H16a, rbias3, cursor, pks, gwa, X4, asv, adv);

  // ---- GAT softmax+aggregate then transform+GEMM (probe on ab2) ----
  k_gs2<<<dim3(NN/4),256,0,stream>>>(cursor, pks, asv, adv, X4, xagg);
  k_ab2<<<dim3(NN/16),256,0,stream>>>(xagg, gat_w, gat_b, Bt16, P16, zbuf, REPS);

  // ---- per-edge head (probe) ----
  k_edge<<<dim3((EE+15)/16),256,0,stream>>>(ei, P16, b1, w2, b2, out, zbuf, REPS);
}

// Round 14
// 176.427 us; speedup vs baseline: 2.9813x; 2.9813x over previous
//
#include <hip/hip_runtime.h>
#include <math.h>

#define NN 6000
#define EE 100000
#define ELL (EE + NN)   // edges + self loops for GAT
#define CAP 64          // bucket-CSR capacity per node (max deg ~45 << 64)

// packed CSR entry: src (13b) | rel<<13 | self<<14
#define PK_SRC(p)  ((p) & 0x1FFF)
#define PK_REL(p)  (((p) >> 13) & 1)
#define PK_SELF(p) ((p) & 0x4000)

typedef __attribute__((ext_vector_type(8))) short frag8;           // 8 bf16 (4 VGPR)
typedef __attribute__((ext_vector_type(4))) float f32x4;
typedef __attribute__((ext_vector_type(8))) unsigned short u16x8;  // 16B of bf16

__device__ __forceinline__ unsigned short f2bf(float f){
  unsigned u = __float_as_uint(f);
  unsigned r = u + 0x7FFFu + ((u >> 16) & 1u);   // round-to-nearest-even
  return (unsigned short)(r >> 16);
}
__device__ __forceinline__ float bf2f(unsigned short s){
  return __uint_as_float(((unsigned)s) << 16);
}

// ---- fused prep: bucket-CSR fill + W0 bf16 + Wcat + w1->Bt16 + gwa + gwT16 ----
__global__ void k_pdc(const int* __restrict__ ei, const int* __restrict__ et,
                      int* __restrict__ cursor, int* __restrict__ pks,
                      const float* __restrict__ basis0, const float* __restrict__ comp0,
                      const float* __restrict__ b1,const float* __restrict__ c1,const float* __restrict__ r1,
                      const float* __restrict__ b2,const float* __restrict__ c2,const float* __restrict__ r2,
                      const float* __restrict__ b3,const float* __restrict__ c3,const float* __restrict__ r3,
                      const float* __restrict__ w1,
                      const float* __restrict__ gw, const float* __restrict__ a_src,
                      const float* __restrict__ a_dst,
                      unsigned short* __restrict__ W016, float* __restrict__ Wcat,
                      unsigned short* __restrict__ Bt16, float* __restrict__ gwa,
                      unsigned short* __restrict__ gwT16){
  int t0 = blockIdx.x*256 + threadIdx.x;
  if (t0 < ELL){
    int d, pk;
    if (t0 < EE){
      d = ei[EE+t0];
      pk = ei[t0] | (et[t0] << 13);
    } else {
      d = t0 - EE; pk = d | 0x4000;
    }
    int pos = atomicAdd(&cursor[d], 1);
    pks[d*CAP + pos] = pk;
  }
  if (t0 < 2*NN*32){
    int r = t0 / (NN*32);
    int no = t0 - r*(NN*32);
    float acc = 0.f;
    #pragma unroll
    for (int b=0;b<4;b++) acc += comp0[r*4+b] * basis0[b*(NN*32)+no];
    W016[t0] = f2bf(acc);
    return;
  }
  int tw = t0 - 2*NN*32;
  if (tw < 24576){
    const float *bb,*cc,*rr; int I,O; int t = tw;
    if (tw < 6144)        { bb=b1;cc=c1;rr=r1;I=32;O=64; }
    else if (tw < 18432)  { bb=b2;cc=c2;rr=r2;I=64;O=64; t -= 6144; }
    else                  { bb=b3;cc=c3;rr=r3;I=64;O=32; t -= 18432; }
    int C = 3*O;
    int i = t / C; int col = t - i*C;
    float v;
    if (col < O) v = rr[i*O + col];
    else {
      int r = (col - O) / O; int o = col - O - r*O;
      v = 0.f;
      #pragma unroll
      for (int b=0;b<4;b++) v += cc[r*4+b]*bb[(b*I+i)*O + o];
    }
    Wcat[tw] = v;
    return;
  }
  int tb = tw - 24576;           // Bt16: [n][k], n in [0,256), k in [0,512)
  if (tb < 256*512){
    int n = tb >> 9, k = tb & 511;
    float v = (n < 128) ? w1[k*128 + n] : w1[(512+k)*128 + (n-128)];
    Bt16[tb] = f2bf(v);
    return;
  }
  int ti = tb - 256*512;         // gwa: 4096 threads = 64 waves, 1 wave/output
  if (ti < 64*64){               // (section start is 256-aligned in the grid)
    int w = ti >> 6, lane = ti & 63;
    const float* av = (w < 32) ? a_src : a_dst;
    int i = w & 31;
    float s = 0.f;
    #pragma unroll
    for (int q=0;q<8;q++){
      int k = lane + q*64;
      s += gw[i*512 + k]*av[k];
    }
    #pragma unroll
    for (int off=32;off>0;off>>=1) s += __shfl_xor(s, off, 64);
    if (lane == 0) gwa[w] = s;
    return;
  }
  int tg = ti - 64*64;           // gwT16: [col][k] bf16 transpose of gw[32][512]
  if (tg < 512*32){
    int c = tg >> 5, k = tg & 31;
    gwT16[tg] = f2bf(gw[k*512 + c]);
  }
}

// ---- F1: wave-per-node gather (x=I) + nodemm 32x192 -> H16 [N,192] ----
__global__ void __launch_bounds__(512) k_f1(
    const unsigned short* __restrict__ W016, const float* __restrict__ root,
    const float* __restrict__ rbias0,
    const int* __restrict__ degc, const int* __restrict__ pks,
    const float* __restrict__ Wc, unsigned short* __restrict__ Hout){
  __shared__ float sx[8*32];
  int n0 = blockIdx.x*8;
  int t = threadIdx.x, nl = t>>6, lane = t&63, o = lane&31, h = lane>>5;
  int n = n0 + nl;
  int r0 = n*CAP, deg = degc[n];
  int pk = (lane < deg) ? pks[r0 + lane] : 0x4000;   // full CSR row in registers
  float a0 = 0.f, a1 = 0.f, c0 = 0.f, c1 = 0.f;
  int trips = (deg + 1) >> 1;                        // edges e = 2*jj + h
  for (int jj = 0; jj < trips; jj += 4){
    int pA = __shfl(pk, 2*jj + h, 64);
    int pB = __shfl(pk, min(2*jj + 2 + h, 63), 64);
    int pC = __shfl(pk, min(2*jj + 4 + h, 63), 64);
    int pD = __shfl(pk, min(2*jj + 6 + h, 63), 64);
    float vA = bf2f(W016[(PK_REL(pA)*NN + PK_SRC(pA))*32 + o]);
    float vB = bf2f(W016[(PK_REL(pB)*NN + PK_SRC(pB))*32 + o]);
    float vC = bf2f(W016[(PK_REL(pC)*NN + PK_SRC(pC))*32 + o]);
    float vD = bf2f(W016[(PK_REL(pD)*NN + PK_SRC(pD))*32 + o]);
    if (!PK_SELF(pA)){ if (PK_REL(pA)==0){ a0 += vA; c0 += 1.f; } else { a1 += vA; c1 += 1.f; } }
    if (!PK_SELF(pB)){ if (PK_REL(pB)==0){ a0 += vB; c0 += 1.f; } else { a1 += vB; c1 += 1.f; } }
    if (!PK_SELF(pC)){ if (PK_REL(pC)==0){ a0 += vC; c0 += 1.f; } else { a1 += vC; c1 += 1.f; } }
    if (!PK_SELF(pD)){ if (PK_REL(pD)==0){ a0 += vD; c0 += 1.f; } else { a1 += vD; c1 += 1.f; } }
  }
  a0 += __shfl_xor(a0, 32, 64); a1 += __shfl_xor(a1, 32, 64);
  c0 += __shfl_xor(c0, 32, 64); c1 += __shfl_xor(c1, 32, 64);
  float v = tanhf(root[n*32+o] + rbias0[o] + a0/fmaxf(c0,1.f) + a1/fmaxf(c1,1.f));
  if (h == 0) sx[nl*32+o] = v;
  __syncthreads();
  if (t < 384){
    int col = t % 192, grp = t / 192;        // grp 0/1 -> nodes grp*4 .. +3
    float acc[4] = {0,0,0,0};
    for (int i=0;i<32;i++){
      float w = Wc[i*192 + col];
      #pragma unroll
      for (int tt=0;tt<4;tt++) acc[tt] += sx[(grp*4+tt)*32+i]*w;
    }
    #pragma unroll
    for (int tt=0;tt<4;tt++) Hout[(n0+grp*4+tt)*192 + col] = f2bf(acc[tt]);
  }
}

// ---- F2: wave-per-node ragg<64> (Hin stride 192) + nodemm 64x192, 8 nodes/blk ----
__global__ void __launch_bounds__(512) k_f2(
    const unsigned short* __restrict__ Hin, const float* __restrict__ rbias,
    const int* __restrict__ degc, const int* __restrict__ pks,
    const float* __restrict__ Wc, unsigned short* __restrict__ Hout){
  __shared__ float sx[8*64];
  int n0 = blockIdx.x*8;
  int t = threadIdx.x, nl = t>>6, lane = t&63, o0 = (lane&31)*2, h = lane>>5;
  int n = n0 + nl;
  int r0 = n*CAP, deg = degc[n];
  int pk = (lane < deg) ? pks[r0 + lane] : 0x4000;
  float a00=0.f, a01=0.f, a10=0.f, a11=0.f, c0=0.f, c1=0.f;
  int trips = (deg + 1) >> 1;
  for (int jj = 0; jj < trips; jj += 4){
    int pA = __shfl(pk, 2*jj + h, 64);
    int pB = __shfl(pk, min(2*jj + 2 + h, 63), 64);
    int pC = __shfl(pk, min(2*jj + 4 + h, 63), 64);
    int pD = __shfl(pk, min(2*jj + 6 + h, 63), 64);
    unsigned hvA = *(const unsigned*)&Hin[PK_SRC(pA)*192 + 64 + PK_REL(pA)*64 + o0];
    unsigned hvB = *(const unsigned*)&Hin[PK_SRC(pB)*192 + 64 + PK_REL(pB)*64 + o0];
    unsigned hvC = *(const unsigned*)&Hin[PK_SRC(pC)*192 + 64 + PK_REL(pC)*64 + o0];
    unsigned hvD = *(const unsigned*)&Hin[PK_SRC(pD)*192 + 64 + PK_REL(pD)*64 + o0];
    if (!PK_SELF(pA)){
      float v0 = bf2f((unsigned short)(hvA & 0xFFFF));
      float v1 = bf2f((unsigned short)(hvA >> 16));
      if (PK_REL(pA)==0){ a00 += v0; a01 += v1; c0 += 1.f; } else { a10 += v0; a11 += v1; c1 += 1.f; }
    }
    if (!PK_SELF(pB)){
      float v0 = bf2f((unsigned short)(hvB & 0xFFFF));
      float v1 = bf2f((unsigned short)(hvB >> 16));
      if (PK_REL(pB)==0){ a00 += v0; a01 += v1; c0 += 1.f; } else { a10 += v0; a11 += v1; c1 += 1.f; }
    }
    if (!PK_SELF(pC)){
      float v0 = bf2f((unsigned short)(hvC & 0xFFFF));
      float v1 = bf2f((unsigned short)(hvC >> 16));
      if (PK_REL(pC)==0){ a00 += v0; a01 += v1; c0 += 1.f; } else { a10 += v0; a11 += v1; c1 += 1.f; }
    }
    if (!PK_SELF(pD)){
      float v0 = bf2f((unsigned short)(hvD & 0xFFFF));
      float v1 = bf2f((unsigned short)(hvD >> 16));
      if (PK_REL(pD)==0){ a00 += v0; a01 += v1; c0 += 1.f; } else { a10 += v0; a11 += v1; c1 += 1.f; }
    }
  }
  a00 += __shfl_xor(a00, 32, 64); a01 += __shfl_xor(a01, 32, 64);
  a10 += __shfl_xor(a10, 32, 64); a11 += __shfl_xor(a11, 32, 64);
  c0  += __shfl_xor(c0, 32, 64);  c1  += __shfl_xor(c1, 32, 64);
  float i0 = 1.f/fmaxf(c0,1.f), i1 = 1.f/fmaxf(c1,1.f);
  if (h == 0){
    sx[nl*64+o0]   = tanhf(bf2f(Hin[n*192+o0])   + rbias[o0]   + a00*i0 + a10*i1);
    sx[nl*64+o0+1] = tanhf(bf2f(Hin[n*192+o0+1]) + rbias[o0+1] + a01*i0 + a11*i1);
  }
  __syncthreads();
  if (t < 384){
    int col = t % 192, grp = t / 192;        // grp 0/1 -> nodes grp*4 .. +3
    float acc[4] = {0,0,0,0};
    for (int i=0;i<64;i++){
      float w = Wc[i*192 + col];
      #pragma unroll
      for (int tt=0;tt<4;tt++) acc[tt] += sx[(grp*4+tt)*64+i]*w;
    }
    #pragma unroll
    for (int tt=0;tt<4;tt++) Hout[(n0+grp*4+tt)*192 + col] = f2bf(acc[tt]);
  }
}

// ---- F3: wave-per-node ragg<64> (Hin stride 192) + nodemm 64x96, 8 nodes/blk ----
__global__ void __launch_bounds__(512) k_f3(
    const unsigned short* __restrict__ Hin, const float* __restrict__ rbias,
    const int* __restrict__ degc, const int* __restrict__ pks,
    const float* __restrict__ Wc, unsigned short* __restrict__ Hout){
  __shared__ float sx[8*64];
  int n0 = blockIdx.x*8;
  int t = threadIdx.x, nl = t>>6, lane = t&63, o0 = (lane&31)*2, h = lane>>5;
  int n = n0 + nl;
  int r0 = n*CAP, deg = degc[n];
  int pk = (lane < deg) ? pks[r0 + lane] : 0x4000;
  float a00=0.f, a01=0.f, a10=0.f, a11=0.f, c0=0.f, c1=0.f;
  int trips = (deg + 1) >> 1;
  for (int jj = 0; jj < trips; jj += 4){
    int pA = __shfl(pk, 2*jj + h, 64);
    int pB = __shfl(pk, min(2*jj + 2 + h, 63), 64);
    int pC = __shfl(pk, min(2*jj + 4 + h, 63), 64);
    int pD = __shfl(pk, min(2*jj + 6 + h, 63), 64);
    unsigned hvA = *(const unsigned*)&Hin[PK_SRC(pA)*192 + 64 + PK_REL(pA)*64 + o0];
    unsigned hvB = *(const unsigned*)&Hin[PK_SRC(pB)*192 + 64 + PK_REL(pB)*64 + o0];
    unsigned hvC = *(const unsigned*)&Hin[PK_SRC(pC)*192 + 64 + PK_REL(pC)*64 + o0];
    unsigned hvD = *(const unsigned*)&Hin[PK_SRC(pD)*192 + 64 + PK_REL(pD)*64 + o0];
    if (!PK_SELF(pA)){
      float v0 = bf2f((unsigned short)(hvA & 0xFFFF));
      float v1 = bf2f((unsigned short)(hvA >> 16));
      if (PK_REL(pA)==0){ a00 += v0; a01 += v1; c0 += 1.f; } else { a10 += v0; a11 += v1; c1 += 1.f; }
    }
    if (!PK_SELF(pB)){
      float v0 = bf2f((unsigned short)(hvB & 0xFFFF));
      float v1 = bf2f((unsigned short)(hvB >> 16));
      if (PK_REL(pB)==0){ a00 += v0; a01 += v1; c0 += 1.f; } else { a10 += v0; a11 += v1; c1 += 1.f; }
    }
    if (!PK_SELF(pC)){
      float v0 = bf2f((unsigned short)(hvC & 0xFFFF));
      float v1 = bf2f((unsigned short)(hvC >> 16));
      if (PK_REL(pC)==0){ a00 += v0; a01 += v1; c0 += 1.f; } else { a10 += v0; a11 += v1; c1 += 1.f; }
    }
    if (!PK_SELF(pD)){
      float v0 = bf2f((unsigned short)(hvD & 0xFFFF));
      float v1 = bf2f((unsigned short)(hvD >> 16));
      if (PK_REL(pD)==0){ a00 += v0; a01 += v1; c0 += 1.f; } else { a10 += v0; a11 += v1; c1 += 1.f; }
    }
  }
  a00 += __shfl_xor(a00, 32, 64); a01 += __shfl_xor(a01, 32, 64);
  a10 += __shfl_xor(a10, 32, 64); a11 += __shfl_xor(a11, 32, 64);
  c0  += __shfl_xor(c0, 32, 64);  c1  += __shfl_xor(c1, 32, 64);
  float i0 = 1.f/fmaxf(c0,1.f), i1 = 1.f/fmaxf(c1,1.f);
  if (h == 0){
    sx[nl*64+o0]   = tanhf(bf2f(Hin[n*192+o0])   + rbias[o0]   + a00*i0 + a10*i1);
    sx[nl*64+o0+1] = tanhf(bf2f(Hin[n*192+o0+1]) + rbias[o0+1] + a01*i0 + a11*i1);
  }
  __syncthreads();
  if (t < 384){
    int c = t % 96, grp = t / 96;            // grp 0..3 -> nodes grp*2 .. +1
    float acc[2] = {0,0};
    for (int i=0;i<64;i++){
      float w = Wc[i*96 + c];
      #pragma unroll
      for (int tt=0;tt<2;tt++) acc[tt] += sx[(grp*2+tt)*64+i]*w;
    }
    #pragma unroll
    for (int tt=0;tt<2;tt++) Hout[(n0+grp*2+tt)*96 + c] = f2bf(acc[tt]);
  }
}

// ---- F4': wave-per-node ragg<32> (stride 96) -> X4 bf16 [N,32] + GAT scores ----
__global__ void __launch_bounds__(256) k_f4(
    const unsigned short* __restrict__ Hin, const float* __restrict__ rbias,
    const int* __restrict__ degc, const int* __restrict__ pks,
    const float* __restrict__ gwa,
    unsigned short* __restrict__ X4, float* __restrict__ asv, float* __restrict__ adv){
  int n0 = blockIdx.x*4;
  int t = threadIdx.x, nl = t>>6, lane = t&63, o = lane&31, h = lane>>5;
  int n = n0 + nl;
  int r0 = n*CAP, deg = degc[n];
  int pk = (lane < deg) ? pks[r0 + lane] : 0x4000;
  float a0=0.f, a1=0.f, c0=0.f, c1=0.f;
  int trips = (deg + 1) >> 1;
  for (int jj = 0; jj < trips; jj += 4){
    int pA = __shfl(pk, 2*jj + h, 64);
    int pB = __shfl(pk, min(2*jj + 2 + h, 63), 64);
    int pC = __shfl(pk, min(2*jj + 4 + h, 63), 64);
    int pD = __shfl(pk, min(2*jj + 6 + h, 63), 64);
    float vA = bf2f(Hin[PK_SRC(pA)*96 + 32 + PK_REL(pA)*32 + o]);
    float vB = bf2f(Hin[PK_SRC(pB)*96 + 32 + PK_REL(pB)*32 + o]);
    float vC = bf2f(Hin[PK_SRC(pC)*96 + 32 + PK_REL(pC)*32 + o]);
    float vD = bf2f(Hin[PK_SRC(pD)*96 + 32 + PK_REL(pD)*32 + o]);
    if (!PK_SELF(pA)){ if (PK_REL(pA)==0){ a0 += vA; c0 += 1.f; } else { a1 += vA; c1 += 1.f; } }
    if (!PK_SELF(pB)){ if (PK_REL(pB)==0){ a0 += vB; c0 += 1.f; } else { a1 += vB; c1 += 1.f; } }
    if (!PK_SELF(pC)){ if (PK_REL(pC)==0){ a0 += vC; c0 += 1.f; } else { a1 += vC; c1 += 1.f; } }
    if (!PK_SELF(pD)){ if (PK_REL(pD)==0){ a0 += vD; c0 += 1.f; } else { a1 += vD; c1 += 1.f; } }
  }
  a0 += __shfl_xor(a0, 32, 64); a1 += __shfl_xor(a1, 32, 64);
  c0 += __shfl_xor(c0, 32, 64); c1 += __shfl_xor(c1, 32, 64);
  float v = tanhf(bf2f(Hin[n*96+o]) + rbias[o] + a0/fmaxf(c0,1.f) + a1/fmaxf(c1,1.f));
  if (h == 0) X4[n*32 + o] = f2bf(v);
  // scores: half 0 reduces v*gwa_src, half 1 reduces v*gwa_dst (both have v)
  float s = v * gwa[h*32 + o];
  #pragma unroll
  for (int off=16;off>0;off>>=1) s += __shfl_xor(s, off, 64);  // stays in-half
  if (lane == 0)       asv[n] = s;
  else if (lane == 32) adv[n] = s;
}

// ---- GS2: GAT softmax + aggregate on X4, 1 wave per node (6000 waves) ----
// Output xagg16 bf16 [N][32] — feeds ab2's MFMA A-operand directly.
__global__ void __launch_bounds__(256) k_gs2(
    const int* __restrict__ degc, const int* __restrict__ pks,
    const float* __restrict__ asv, const float* __restrict__ adv,
    const unsigned short* __restrict__ X4, unsigned short* __restrict__ xagg16){
  int t = threadIdx.x, w = t>>6, lane = t&63;
  int n = blockIdx.x*4 + w;
  int r0 = n*CAP, deg = degc[n];
  float advn = adv[n];
  int pk  = (lane < deg) ? pks[r0 + lane] : -1;
  int src = (pk >= 0) ? PK_SRC(pk) : 0;
  float aa = -1e30f;
  if (pk >= 0){
    float a = asv[src] + advn;
    aa = (a >= 0.f) ? a : 0.2f*a;
  }
  float m = aa;
  #pragma unroll
  for (int off=32;off>0;off>>=1) m = fmaxf(m, __shfl_xor(m,off,64));
  float ex = (pk >= 0) ? expf(aa - m) : 0.f;
  float se = ex;
  #pragma unroll
  for (int off=32;off>0;off>>=1) se += __shfl_xor(se,off,64);
  float inv = 1.f / fmaxf(se, 1e-16f);
  int c = lane & 31, h = lane >> 5;
  float acc = 0.f;
  int trips = (deg + 1) >> 1;
  for (int jj = 0; jj < trips; jj += 4){
    float cfA = __shfl(ex, 2*jj + h, 64);
    int   svA = __shfl(src, 2*jj + h, 64);
    float cfB = __shfl(ex, min(2*jj + 2 + h, 63), 64);
    int   svB = __shfl(src, min(2*jj + 2 + h, 63), 64);
    float cfC = __shfl(ex, min(2*jj + 4 + h, 63), 64);
    int   svC = __shfl(src, min(2*jj + 4 + h, 63), 64);
    float cfD = __shfl(ex, min(2*jj + 6 + h, 63), 64);
    int   svD = __shfl(src, min(2*jj + 6 + h, 63), 64);
    float vA = bf2f(X4[svA*32 + c]);
    float vB = bf2f(X4[svB*32 + c]);
    float vC = bf2f(X4[svC*32 + c]);
    float vD = bf2f(X4[svD*32 + c]);
    acc += cfA * vA;
    acc += cfB * vB;
    acc += cfC * vC;
    acc += cfD * vD;
  }
  acc += __shfl_xor(acc, 32, 64);
  if (h == 0) xagg16[n*32 + c] = f2bf(acc * inv);
}

// ---- AB2: gout = relu(xagg@gw + b) via MFMA (16x512x32) into LDS, then
// P16 tile = gout @ Bt16^T via MFMA. Phase B now 8 MFMA/wave instead of
// 512 scalar LDS reads + 1024 VALU FMAs per THREAD (R13 probe: 20.6 us). ----
__global__ void __launch_bounds__(256) k_ab2(
    const unsigned short* __restrict__ xagg16, const unsigned short* __restrict__ gwT16,
    const float* __restrict__ gat_b, const unsigned short* __restrict__ Bt16,
    unsigned short* __restrict__ P16){
  __shared__ unsigned short go[16*520];
  int t = threadIdx.x, w = t>>6, lane = t&63;
  int n0 = blockIdx.x*16;
  int r = lane & 15, kq = (lane >> 4) * 8;
  // ---- Phase B: rows 0-15 x cols [w*128, w*128+128) = 8 MFMA (16x16, K=32) ----
  {
    frag8 a = *(const frag8*)&xagg16[(size_t)(n0 + r)*32 + kq];   // reused 8x
    int rowb = (lane >> 4) * 4;
    #pragma unroll
    for (int m = 0; m < 8; m++){
      int c0 = w*128 + m*16;
      frag8 b = *(const frag8*)&gwT16[(size_t)(c0 + r)*32 + kq];
      f32x4 c4 = {0,0,0,0};
      c4 = __builtin_amdgcn_mfma_f32_16x16x32_bf16(a, b, c4, 0, 0, 0);
      float bb = gat_b[c0 + r];          // D col = lane&15 = r
      #pragma unroll
      for (int i=0;i<4;i++)
        go[(rowb+i)*520 + c0 + r] = f2bf(fmaxf(c4[i] + bb, 0.f));
    }
  }
  __syncthreads();
  // ---- Phase C: P16 tile = go(16x512) @ Bt16^T; wave w -> cols [w*64,+64) ----
  {
    const unsigned short* arow  = go + r*520 + kq;
    const unsigned short* bbase = Bt16 + (size_t)(w*64 + r)*512 + kq;
    f32x4 acc0 = {0,0,0,0}, acc1 = {0,0,0,0}, acc2 = {0,0,0,0}, acc3 = {0,0,0,0};
    for (int k = 0; k < 512; k += 32){
      frag8 a  = *(const frag8*)(arow + k);
      frag8 b0 = *(const frag8*)(bbase + k);
      frag8 b1 = *(const frag8*)(bbase + 16*512 + k);
      frag8 b2 = *(const frag8*)(bbase + 32*512 + k);
      frag8 b3 = *(const frag8*)(bbase + 48*512 + k);
      acc0 = __builtin_amdgcn_mfma_f32_16x16x32_bf16(a, b0, acc0, 0, 0, 0);
      acc1 = __builtin_amdgcn_mfma_f32_16x16x32_bf16(a, b1, acc1, 0, 0, 0);
      acc2 = __builtin_amdgcn_mfma_f32_16x16x32_bf16(a, b2, acc2, 0, 0, 0);
      acc3 = __builtin_amdgcn_mfma_f32_16x16x32_bf16(a, b3, acc3, 0, 0, 0);
    }
    int rowb = n0 + (lane >> 4)*4;
    int col  = w*64 + r;
    #pragma unroll
    for (int i=0;i<4;i++){
      P16[(size_t)(rowb+i)*256 + col     ] = f2bf(acc0[i]);
      P16[(size_t)(rowb+i)*256 + col + 16] = f2bf(acc1[i]);
      P16[(size_t)(rowb+i)*256 + col + 32] = f2bf(acc2[i]);
      P16[(size_t)(rowb+i)*256 + col + 48] = f2bf(acc3[i]);
    }
  }
}

// per-edge MLP head: 16 lanes/edge, bf16 P loads
__global__ void k_edge(const int* __restrict__ ei, const unsigned short* __restrict__ P16,
                       const float* __restrict__ b1,
                       const float* __restrict__ w2, const float* __restrict__ b2,
                       float* __restrict__ out){
  int e = blockIdx.x*16 + (threadIdx.x >> 4);
  int l = threadIdx.x & 15;            // lane covers channels [l*8, l*8+8)
  if (e >= EE) return;
  int s = ei[e], d = ei[EE+e];
  const u16x8 Av = *(const u16x8*)&P16[(size_t)s*256 + l*8];
  const u16x8 Bv = *(const u16x8*)&P16[(size_t)d*256 + 128 + l*8];
  const float4 b1a = *(const float4*)&b1[l*8];
  const float4 b1b = *(const float4*)&b1[l*8+4];
  const float4 w2a = *(const float4*)&w2[l*8];
  const float4 w2b = *(const float4*)&w2[l*8+4];
  float h0 = fmaxf(bf2f(Av[0])+bf2f(Bv[0])+b1a.x, 0.f);
  float h1 = fmaxf(bf2f(Av[1])+bf2f(Bv[1])+b1a.y, 0.f);
  float h2 = fmaxf(bf2f(Av[2])+bf2f(Bv[2])+b1a.z, 0.f);
  float h3 = fmaxf(bf2f(Av[3])+bf2f(Bv[3])+b1a.w, 0.f);
  float h4 = fmaxf(bf2f(Av[4])+bf2f(Bv[4])+b1b.x, 0.f);
  float h5 = fmaxf(bf2f(Av[5])+bf2f(Bv[5])+b1b.y, 0.f);
  float h6 = fmaxf(bf2f(Av[6])+bf2f(Bv[6])+b1b.z, 0.f);
  float h7 = fmaxf(bf2f(Av[7])+bf2f(Bv[7])+b1b.w, 0.f);
  float acc = h0*w2a.x + h1*w2a.y + h2*w2a.z + h3*w2a.w
            + h4*w2b.x + h5*w2b.y + h6*w2b.z + h7*w2b.w;
  #pragma unroll
  for (int m=8;m>0;m>>=1) acc += __shfl_xor(acc,m,64);
  if (l==0) out[e] = 1.f/(1.f + expf(-(acc + b2[0])));
}

extern "C" void kernel_launch(void* const* d_in, const int* in_sizes, int n_in,
                              void* d_out, int out_size, void* d_ws, size_t ws_size,
                              hipStream_t stream){
  const float* basis0 = (const float*)d_in[0];
  const float* comp0  = (const float*)d_in[1];
  const float* root0  = (const float*)d_in[2];
  const float* rbias0 = (const float*)d_in[3];
  const float* basis1 = (const float*)d_in[4];
  const float* comp1  = (const float*)d_in[5];
  const float* root1  = (const float*)d_in[6];
  const float* rbias1 = (const float*)d_in[7];
  const float* basis2 = (const float*)d_in[8];
  const float* comp2  = (const float*)d_in[9];
  const float* root2  = (const float*)d_in[10];
  const float* rbias2 = (const float*)d_in[11];
  const float* basis3 = (const float*)d_in[12];
  const float* comp3  = (const float*)d_in[13];
  const float* root3  = (const float*)d_in[14];
  const float* rbias3 = (const float*)d_in[15];
  const float* gat_w = (const float*)d_in[16];
  const float* a_src = (const float*)d_in[17];
  const float* a_dst = (const float*)d_in[18];
  const float* gat_b = (const float*)d_in[19];
  const float* w1 = (const float*)d_in[20];
  const float* b1 = (const float*)d_in[21];
  const float* w2 = (const float*)d_in[22];
  const float* b2 = (const float*)d_in[23];
  const int* ei = (const int*)d_in[24];
  const int* et = (const int*)d_in[25];
  float* out = (float*)d_out;

  // workspace carve-up (16B-aligned sections)
  float* p = (float*)d_ws;
  int* cursor = (int*)p; p += NN;              // doubles as degree after k_pdc
  int* pks    = (int*)p; p += NN*CAP;          // bucket CSR (64 slots/node)
  unsigned short* W016 = (unsigned short*)p; p += NN*32;       // 2*NN*32 bf16
  float* Wcat = p; p += 24576;
  unsigned short* Bt16 = (unsigned short*)p; p += 256*512/2;
  unsigned short* H16a = (unsigned short*)p; p += NN*96;       // NN*192 bf16
  unsigned short* H16b = (unsigned short*)p; p += NN*96;       // NN*192 bf16
  unsigned short* X4   = (unsigned short*)p; p += NN*16;       // NN*32 bf16
  float* gwa  = p; p += 64;                    // gw@a_src (32) + gw@a_dst (32)
  unsigned short* gwT16 = (unsigned short*)p; p += 512*32/2;   // gw^T bf16 [512][32]
  float* asv  = p; p += NN;
  float* adv  = p; p += NN;
  unsigned short* xagg16 = (unsigned short*)p; p += NN*16;     // NN*32 bf16
  unsigned short* P16 = (unsigned short*)p; p += NN*128;       // NN*256 bf16

  auto grid = [](long long n){ return dim3((unsigned)((n + 255)/256)); };

  // ---- zero cursor only, then single fused prep kernel ----
  hipMemsetAsync(cursor, 0, (size_t)NN*sizeof(int), stream);
  k_pdc<<<grid(2LL*NN*32 + 24576 + 256*512 + 64*64 + 512*32),256,0,stream>>>(
        ei, et, cursor, pks,
        basis0, comp0, basis1,comp1,root1, basis2,comp2,root2,
        basis3,comp3,root3, w1, gat_w, a_src, a_dst, W016, Wcat, Bt16, gwa, gwT16);

  // ---- RGCN stack: wave-per-node gathers; 8 nodes/block (R11 config) ----
  k_f1<<<dim3(NN/8),512,0,stream>>>(W016, root0, rbias0, cursor, pks, Wcat, H16a);
  k_f2<<<dim3(NN/8),512,0,stream>>>(H16a, rbias1, cursor, pks, Wcat + 6144, H16b);
  k_f3<<<dim3(NN/8),512,0,stream>>>(H16b, rbias2, cursor, pks, Wcat + 18432, H16a);
  k_f4<<<dim3(NN/4),256,0,stream>>>(H16a, rbias3, cursor, pks, gwa, X4, asv, adv);

  // ---- GAT softmax+aggregate (bf16 out) then dual-MFMA transform ----
  k_gs2<<<dim3(NN/4),256,0,stream>>>(cursor, pks, asv, adv, X4, xagg16);
  k_ab2<<<dim3(NN/16),256,0,stream>>>(xagg16, gwT16, gat_b, Bt16, P16);

  // ---- per-edge head ----
  k_edge<<<dim3((EE+15)/16),256,0,stream>>>(ei, P16, b1, w2, b2, out);
}

// Round 15
// 171.832 us; speedup vs baseline: 3.0611x; 1.0267x over previous
//
#include <hip/hip_runtime.h>
#include <math.h>

#define NN 6000
#define EE 100000
#define ELL (EE + NN)   // edges + self loops for GAT
#define CAP 64          // bucket-CSR capacity per node (max deg ~45 << 64)

// packed CSR entry: src (13b) | rel<<13 | self<<14
#define PK_SRC(p)  ((p) & 0x1FFF)
#define PK_REL(p)  (((p) >> 13) & 1)
#define PK_SELF(p) ((p) & 0x4000)

typedef __attribute__((ext_vector_type(8))) short frag8;           // 8 bf16 (4 VGPR)
typedef __attribute__((ext_vector_type(4))) float f32x4;
typedef __attribute__((ext_vector_type(8))) unsigned short u16x8;  // 16B of bf16

__device__ __forceinline__ unsigned short f2bf(float f){
  unsigned u = __float_as_uint(f);
  unsigned r = u + 0x7FFFu + ((u >> 16) & 1u);   // round-to-nearest-even
  return (unsigned short)(r >> 16);
}
__device__ __forceinline__ float bf2f(unsigned short s){
  return __uint_as_float(((unsigned)s) << 16);
}

// ---- fused prep: bucket-CSR fill + W0 bf16 + Wcat + w1->Bt16 + gwa + gwT16 ----
// Bt16 section: k=tb>>8, n=tb&255 -> consecutive lanes read CONTIGUOUS w1
// (was stride-512B, ~64x fetch amplification of a cold 512KB read); the
// scattered Bt16 stores are absorbed by L2 (256KB resident).
__global__ void k_pdc(const int* __restrict__ ei, const int* __restrict__ et,
                      int* __restrict__ cursor, int* __restrict__ pks,
                      const float* __restrict__ basis0, const float* __restrict__ comp0,
                      const float* __restrict__ b1,const float* __restrict__ c1,const float* __restrict__ r1,
                      const float* __restrict__ b2,const float* __restrict__ c2,const float* __restrict__ r2,
                      const float* __restrict__ b3,const float* __restrict__ c3,const float* __restrict__ r3,
                      const float* __restrict__ w1,
                      const float* __restrict__ gw, const float* __restrict__ a_src,
                      const float* __restrict__ a_dst,
                      unsigned short* __restrict__ W016, float* __restrict__ Wcat,
                      unsigned short* __restrict__ Bt16, float* __restrict__ gwa,
                      unsigned short* __restrict__ gwT16){
  int t0 = blockIdx.x*256 + threadIdx.x;
  if (t0 < ELL){
    int d, pk;
    if (t0 < EE){
      d = ei[EE+t0];
      pk = ei[t0] | (et[t0] << 13);
    } else {
      d = t0 - EE; pk = d | 0x4000;
    }
    int pos = atomicAdd(&cursor[d], 1);
    pks[d*CAP + pos] = pk;
  }
  if (t0 < 2*NN*32){
    int r = t0 / (NN*32);
    int no = t0 - r*(NN*32);
    float acc = 0.f;
    #pragma unroll
    for (int b=0;b<4;b++) acc += comp0[r*4+b] * basis0[b*(NN*32)+no];
    W016[t0] = f2bf(acc);
    return;
  }
  int tw = t0 - 2*NN*32;
  if (tw < 24576){
    const float *bb,*cc,*rr; int I,O; int t = tw;
    if (tw < 6144)        { bb=b1;cc=c1;rr=r1;I=32;O=64; }
    else if (tw < 18432)  { bb=b2;cc=c2;rr=r2;I=64;O=64; t -= 6144; }
    else                  { bb=b3;cc=c3;rr=r3;I=64;O=32; t -= 18432; }
    int C = 3*O;
    int i = t / C; int col = t - i*C;
    float v;
    if (col < O) v = rr[i*O + col];
    else {
      int r = (col - O) / O; int o = col - O - r*O;
      v = 0.f;
      #pragma unroll
      for (int b=0;b<4;b++) v += cc[r*4+b]*bb[(b*I+i)*O + o];
    }
    Wcat[tw] = v;
    return;
  }
  int tb = tw - 24576;           // Bt16: [n][k], n in [0,256), k in [0,512)
  if (tb < 256*512){
    int k = tb >> 8, n = tb & 255;           // coalesced w1 reads
    float v = (n < 128) ? w1[k*128 + n] : w1[(512+k)*128 + (n-128)];
    Bt16[n*512 + k] = f2bf(v);
    return;
  }
  int ti = tb - 256*512;         // gwa: 4096 threads = 64 waves, 1 wave/output
  if (ti < 64*64){               // (section start is 256-aligned in the grid)
    int w = ti >> 6, lane = ti & 63;
    const float* av = (w < 32) ? a_src : a_dst;
    int i = w & 31;
    float s = 0.f;
    #pragma unroll
    for (int q=0;q<8;q++){
      int k = lane + q*64;
      s += gw[i*512 + k]*av[k];
    }
    #pragma unroll
    for (int off=32;off>0;off>>=1) s += __shfl_xor(s, off, 64);
    if (lane == 0) gwa[w] = s;
    return;
  }
  int tg = ti - 64*64;           // gwT16: [col][k] bf16 transpose of gw[32][512]
  if (tg < 512*32){
    int c = tg >> 5, k = tg & 31;
    gwT16[tg] = f2bf(gw[k*512 + c]);
  }
}

// ---- F1: wave-per-node gather (x=I) + nodemm 32x192 -> H16 [N,192] ----
__global__ void __launch_bounds__(512) k_f1(
    const unsigned short* __restrict__ W016, const float* __restrict__ root,
    const float* __restrict__ rbias0,
    const int* __restrict__ degc, const int* __restrict__ pks,
    const float* __restrict__ Wc, unsigned short* __restrict__ Hout){
  __shared__ float sx[8*32];
  int n0 = blockIdx.x*8;
  int t = threadIdx.x, nl = t>>6, lane = t&63, o = lane&31, h = lane>>5;
  int n = n0 + nl;
  int r0 = n*CAP, deg = degc[n];
  int pk = (lane < deg) ? pks[r0 + lane] : 0x4000;   // full CSR row in registers
  float a0 = 0.f, a1 = 0.f, c0 = 0.f, c1 = 0.f;
  int trips = (deg + 1) >> 1;                        // edges e = 2*jj + h
  for (int jj = 0; jj < trips; jj += 4){
    int pA = __shfl(pk, 2*jj + h, 64);
    int pB = __shfl(pk, min(2*jj + 2 + h, 63), 64);
    int pC = __shfl(pk, min(2*jj + 4 + h, 63), 64);
    int pD = __shfl(pk, min(2*jj + 6 + h, 63), 64);
    float vA = bf2f(W016[(PK_REL(pA)*NN + PK_SRC(pA))*32 + o]);
    float vB = bf2f(W016[(PK_REL(pB)*NN + PK_SRC(pB))*32 + o]);
    float vC = bf2f(W016[(PK_REL(pC)*NN + PK_SRC(pC))*32 + o]);
    float vD = bf2f(W016[(PK_REL(pD)*NN + PK_SRC(pD))*32 + o]);
    if (!PK_SELF(pA)){ if (PK_REL(pA)==0){ a0 += vA; c0 += 1.f; } else { a1 += vA; c1 += 1.f; } }
    if (!PK_SELF(pB)){ if (PK_REL(pB)==0){ a0 += vB; c0 += 1.f; } else { a1 += vB; c1 += 1.f; } }
    if (!PK_SELF(pC)){ if (PK_REL(pC)==0){ a0 += vC; c0 += 1.f; } else { a1 += vC; c1 += 1.f; } }
    if (!PK_SELF(pD)){ if (PK_REL(pD)==0){ a0 += vD; c0 += 1.f; } else { a1 += vD; c1 += 1.f; } }
  }
  a0 += __shfl_xor(a0, 32, 64); a1 += __shfl_xor(a1, 32, 64);
  c0 += __shfl_xor(c0, 32, 64); c1 += __shfl_xor(c1, 32, 64);
  float v = tanhf(root[n*32+o] + rbias0[o] + a0/fmaxf(c0,1.f) + a1/fmaxf(c1,1.f));
  if (h == 0) sx[nl*32+o] = v;
  __syncthreads();
  if (t < 384){
    int col = t % 192, grp = t / 192;        // grp 0/1 -> nodes grp*4 .. +3
    float acc[4] = {0,0,0,0};
    for (int i=0;i<32;i++){
      float w = Wc[i*192 + col];
      #pragma unroll
      for (int tt=0;tt<4;tt++) acc[tt] += sx[(grp*4+tt)*32+i]*w;
    }
    #pragma unroll
    for (int tt=0;tt<4;tt++) Hout[(n0+grp*4+tt)*192 + col] = f2bf(acc[tt]);
  }
}

// ---- F2: wave-per-node ragg<64> (Hin stride 192) + nodemm 64x192, 8 nodes/blk ----
__global__ void __launch_bounds__(512) k_f2(
    const unsigned short* __restrict__ Hin, const float* __restrict__ rbias,
    const int* __restrict__ degc, const int* __restrict__ pks,
    const float* __restrict__ Wc, unsigned short* __restrict__ Hout){
  __shared__ float sx[8*64];
  int n0 = blockIdx.x*8;
  int t = threadIdx.x, nl = t>>6, lane = t&63, o0 = (lane&31)*2, h = lane>>5;
  int n = n0 + nl;
  int r0 = n*CAP, deg = degc[n];
  int pk = (lane < deg) ? pks[r0 + lane] : 0x4000;
  float a00=0.f, a01=0.f, a10=0.f, a11=0.f, c0=0.f, c1=0.f;
  int trips = (deg + 1) >> 1;
  for (int jj = 0; jj < trips; jj += 4){
    int pA = __shfl(pk, 2*jj + h, 64);
    int pB = __shfl(pk, min(2*jj + 2 + h, 63), 64);
    int pC = __shfl(pk, min(2*jj + 4 + h, 63), 64);
    int pD = __shfl(pk, min(2*jj + 6 + h, 63), 64);
    unsigned hvA = *(const unsigned*)&Hin[PK_SRC(pA)*192 + 64 + PK_REL(pA)*64 + o0];
    unsigned hvB = *(const unsigned*)&Hin[PK_SRC(pB)*192 + 64 + PK_REL(pB)*64 + o0];
    unsigned hvC = *(const unsigned*)&Hin[PK_SRC(pC)*192 + 64 + PK_REL(pC)*64 + o0];
    unsigned hvD = *(const unsigned*)&Hin[PK_SRC(pD)*192 + 64 + PK_REL(pD)*64 + o0];
    if (!PK_SELF(pA)){
      float v0 = bf2f((unsigned short)(hvA & 0xFFFF));
      float v1 = bf2f((unsigned short)(hvA >> 16));
      if (PK_REL(pA)==0){ a00 += v0; a01 += v1; c0 += 1.f; } else { a10 += v0; a11 += v1; c1 += 1.f; }
    }
    if (!PK_SELF(pB)){
      float v0 = bf2f((unsigned short)(hvB & 0xFFFF));
      float v1 = bf2f((unsigned short)(hvB >> 16));
      if (PK_REL(pB)==0){ a00 += v0; a01 += v1; c0 += 1.f; } else { a10 += v0; a11 += v1; c1 += 1.f; }
    }
    if (!PK_SELF(pC)){
      float v0 = bf2f((unsigned short)(hvC & 0xFFFF));
      float v1 = bf2f((unsigned short)(hvC >> 16));
      if (PK_REL(pC)==0){ a00 += v0; a01 += v1; c0 += 1.f; } else { a10 += v0; a11 += v1; c1 += 1.f; }
    }
    if (!PK_SELF(pD)){
      float v0 = bf2f((unsigned short)(hvD & 0xFFFF));
      float v1 = bf2f((unsigned short)(hvD >> 16));
      if (PK_REL(pD)==0){ a00 += v0; a01 += v1; c0 += 1.f; } else { a10 += v0; a11 += v1; c1 += 1.f; }
    }
  }
  a00 += __shfl_xor(a00, 32, 64); a01 += __shfl_xor(a01, 32, 64);
  a10 += __shfl_xor(a10, 32, 64); a11 += __shfl_xor(a11, 32, 64);
  c0  += __shfl_xor(c0, 32, 64);  c1  += __shfl_xor(c1, 32, 64);
  float i0 = 1.f/fmaxf(c0,1.f), i1 = 1.f/fmaxf(c1,1.f);
  if (h == 0){
    sx[nl*64+o0]   = tanhf(bf2f(Hin[n*192+o0])   + rbias[o0]   + a00*i0 + a10*i1);
    sx[nl*64+o0+1] = tanhf(bf2f(Hin[n*192+o0+1]) + rbias[o0+1] + a01*i0 + a11*i1);
  }
  __syncthreads();
  if (t < 384){
    int col = t % 192, grp = t / 192;        // grp 0/1 -> nodes grp*4 .. +3
    float acc[4] = {0,0,0,0};
    for (int i=0;i<64;i++){
      float w = Wc[i*192 + col];
      #pragma unroll
      for (int tt=0;tt<4;tt++) acc[tt] += sx[(grp*4+tt)*64+i]*w;
    }
    #pragma unroll
    for (int tt=0;tt<4;tt++) Hout[(n0+grp*4+tt)*192 + col] = f2bf(acc[tt]);
  }
}

// ---- F3: wave-per-node ragg<64> (Hin stride 192) + nodemm 64x96, 8 nodes/blk ----
__global__ void __launch_bounds__(512) k_f3(
    const unsigned short* __restrict__ Hin, const float* __restrict__ rbias,
    const int* __restrict__ degc, const int* __restrict__ pks,
    const float* __restrict__ Wc, unsigned short* __restrict__ Hout){
  __shared__ float sx[8*64];
  int n0 = blockIdx.x*8;
  int t = threadIdx.x, nl = t>>6, lane = t&63, o0 = (lane&31)*2, h = lane>>5;
  int n = n0 + nl;
  int r0 = n*CAP, deg = degc[n];
  int pk = (lane < deg) ? pks[r0 + lane] : 0x4000;
  float a00=0.f, a01=0.f, a10=0.f, a11=0.f, c0=0.f, c1=0.f;
  int trips = (deg + 1) >> 1;
  for (int jj = 0; jj < trips; jj += 4){
    int pA = __shfl(pk, 2*jj + h, 64);
    int pB = __shfl(pk, min(2*jj + 2 + h, 63), 64);
    int pC = __shfl(pk, min(2*jj + 4 + h, 63), 64);
    int pD = __shfl(pk, min(2*jj + 6 + h, 63), 64);
    unsigned hvA = *(const unsigned*)&Hin[PK_SRC(pA)*192 + 64 + PK_REL(pA)*64 + o0];
    unsigned hvB = *(const unsigned*)&Hin[PK_SRC(pB)*192 + 64 + PK_REL(pB)*64 + o0];
    unsigned hvC = *(const unsigned*)&Hin[PK_SRC(pC)*192 + 64 + PK_REL(pC)*64 + o0];
    unsigned hvD = *(const unsigned*)&Hin[PK_SRC(pD)*192 + 64 + PK_REL(pD)*64 + o0];
    if (!PK_SELF(pA)){
      float v0 = bf2f((unsigned short)(hvA & 0xFFFF));
      float v1 = bf2f((unsigned short)(hvA >> 16));
      if (PK_REL(pA)==0){ a00 += v0; a01 += v1; c0 += 1.f; } else { a10 += v0; a11 += v1; c1 += 1.f; }
    }
    if (!PK_SELF(pB)){
      float v0 = bf2f((unsigned short)(hvB & 0xFFFF));
      float v1 = bf2f((unsigned short)(hvB >> 16));
      if (PK_REL(pB)==0){ a00 += v0; a01 += v1; c0 += 1.f; } else { a10 += v0; a11 += v1; c1 += 1.f; }
    }
    if (!PK_SELF(pC)){
      float v0 = bf2f((unsigned short)(hvC & 0xFFFF));
      float v1 = bf2f((unsigned short)(hvC >> 16));
      if (PK_REL(pC)==0){ a00 += v0; a01 += v1; c0 += 1.f; } else { a10 += v0; a11 += v1; c1 += 1.f; }
    }
    if (!PK_SELF(pD)){
      float v0 = bf2f((unsigned short)(hvD & 0xFFFF));
      float v1 = bf2f((unsigned short)(hvD >> 16));
      if (PK_REL(pD)==0){ a00 += v0; a01 += v1; c0 += 1.f; } else { a10 += v0; a11 += v1; c1 += 1.f; }
    }
  }
  a00 += __shfl_xor(a00, 32, 64); a01 += __shfl_xor(a01, 32, 64);
  a10 += __shfl_xor(a10, 32, 64); a11 += __shfl_xor(a11, 32, 64);
  c0  += __shfl_xor(c0, 32, 64);  c1  += __shfl_xor(c1, 32, 64);
  float i0 = 1.f/fmaxf(c0,1.f), i1 = 1.f/fmaxf(c1,1.f);
  if (h == 0){
    sx[nl*64+o0]   = tanhf(bf2f(Hin[n*192+o0])   + rbias[o0]   + a00*i0 + a10*i1);
    sx[nl*64+o0+1] = tanhf(bf2f(Hin[n*192+o0+1]) + rbias[o0+1] + a01*i0 + a11*i1);
  }
  __syncthreads();
  if (t < 384){
    int c = t % 96, grp = t / 96;            // grp 0..3 -> nodes grp*2 .. +1
    float acc[2] = {0,0};
    for (int i=0;i<64;i++){
      float w = Wc[i*96 + c];
      #pragma unroll
      for (int tt=0;tt<2;tt++) acc[tt] += sx[(grp*2+tt)*64+i]*w;
    }
    #pragma unroll
    for (int tt=0;tt<2;tt++) Hout[(n0+grp*2+tt)*96 + c] = f2bf(acc[tt]);
  }
}

// ---- F4': wave-per-node ragg<32> (stride 96) -> X4 bf16 [N,32] + GAT scores ----
__global__ void __launch_bounds__(256) k_f4(
    const unsigned short* __restrict__ Hin, const float* __restrict__ rbias,
    const int* __restrict__ degc, const int* __restrict__ pks,
    const float* __restrict__ gwa,
    unsigned short* __restrict__ X4, float* __restrict__ asv, float* __restrict__ adv){
  int n0 = blockIdx.x*4;
  int t = threadIdx.x, nl = t>>6, lane = t&63, o = lane&31, h = lane>>5;
  int n = n0 + nl;
  int r0 = n*CAP, deg = degc[n];
  int pk = (lane < deg) ? pks[r0 + lane] : 0x4000;
  float a0=0.f, a1=0.f, c0=0.f, c1=0.f;
  int trips = (deg + 1) >> 1;
  for (int jj = 0; jj < trips; jj += 4){
    int pA = __shfl(pk, 2*jj + h, 64);
    int pB = __shfl(pk, min(2*jj + 2 + h, 63), 64);
    int pC = __shfl(pk, min(2*jj + 4 + h, 63), 64);
    int pD = __shfl(pk, min(2*jj + 6 + h, 63), 64);
    float vA = bf2f(Hin[PK_SRC(pA)*96 + 32 + PK_REL(pA)*32 + o]);
    float vB = bf2f(Hin[PK_SRC(pB)*96 + 32 + PK_REL(pB)*32 + o]);
    float vC = bf2f(Hin[PK_SRC(pC)*96 + 32 + PK_REL(pC)*32 + o]);
    float vD = bf2f(Hin[PK_SRC(pD)*96 + 32 + PK_REL(pD)*32 + o]);
    if (!PK_SELF(pA)){ if (PK_REL(pA)==0){ a0 += vA; c0 += 1.f; } else { a1 += vA; c1 += 1.f; } }
    if (!PK_SELF(pB)){ if (PK_REL(pB)==0){ a0 += vB; c0 += 1.f; } else { a1 += vB; c1 += 1.f; } }
    if (!PK_SELF(pC)){ if (PK_REL(pC)==0){ a0 += vC; c0 += 1.f; } else { a1 += vC; c1 += 1.f; } }
    if (!PK_SELF(pD)){ if (PK_REL(pD)==0){ a0 += vD; c0 += 1.f; } else { a1 += vD; c1 += 1.f; } }
  }
  a0 += __shfl_xor(a0, 32, 64); a1 += __shfl_xor(a1, 32, 64);
  c0 += __shfl_xor(c0, 32, 64); c1 += __shfl_xor(c1, 32, 64);
  float v = tanhf(bf2f(Hin[n*96+o]) + rbias[o] + a0/fmaxf(c0,1.f) + a1/fmaxf(c1,1.f));
  if (h == 0) X4[n*32 + o] = f2bf(v);
  // scores: half 0 reduces v*gwa_src, half 1 reduces v*gwa_dst (both have v)
  float s = v * gwa[h*32 + o];
  #pragma unroll
  for (int off=16;off>0;off>>=1) s += __shfl_xor(s, off, 64);  // stays in-half
  if (lane == 0)       asv[n] = s;
  else if (lane == 32) adv[n] = s;
}

// ---- GS2: GAT softmax + aggregate on X4, 1 wave per node (6000 waves) ----
// Output xagg16 bf16 [N][32] — feeds ab2's MFMA A-operand directly.
__global__ void __launch_bounds__(256) k_gs2(
    const int* __restrict__ degc, const int* __restrict__ pks,
    const float* __restrict__ asv, const float* __restrict__ adv,
    const unsigned short* __restrict__ X4, unsigned short* __restrict__ xagg16){
  int t = threadIdx.x, w = t>>6, lane = t&63;
  int n = blockIdx.x*4 + w;
  int r0 = n*CAP, deg = degc[n];
  float advn = adv[n];
  int pk  = (lane < deg) ? pks[r0 + lane] : -1;
  int src = (pk >= 0) ? PK_SRC(pk) : 0;
  float aa = -1e30f;
  if (pk >= 0){
    float a = asv[src] + advn;
    aa = (a >= 0.f) ? a : 0.2f*a;
  }
  float m = aa;
  #pragma unroll
  for (int off=32;off>0;off>>=1) m = fmaxf(m, __shfl_xor(m,off,64));
  float ex = (pk >= 0) ? expf(aa - m) : 0.f;
  float se = ex;
  #pragma unroll
  for (int off=32;off>0;off>>=1) se += __shfl_xor(se,off,64);
  float inv = 1.f / fmaxf(se, 1e-16f);
  int c = lane & 31, h = lane >> 5;
  float acc = 0.f;
  int trips = (deg + 1) >> 1;
  for (int jj = 0; jj < trips; jj += 4){
    float cfA = __shfl(ex, 2*jj + h, 64);
    int   svA = __shfl(src, 2*jj + h, 64);
    float cfB = __shfl(ex, min(2*jj + 2 + h, 63), 64);
    int   svB = __shfl(src, min(2*jj + 2 + h, 63), 64);
    float cfC = __shfl(ex, min(2*jj + 4 + h, 63), 64);
    int   svC = __shfl(src, min(2*jj + 4 + h, 63), 64);
    float cfD = __shfl(ex, min(2*jj + 6 + h, 63), 64);
    int   svD = __shfl(src, min(2*jj + 6 + h, 63), 64);
    float vA = bf2f(X4[svA*32 + c]);
    float vB = bf2f(X4[svB*32 + c]);
    float vC = bf2f(X4[svC*32 + c]);
    float vD = bf2f(X4[svD*32 + c]);
    acc += cfA * vA;
    acc += cfB * vB;
    acc += cfC * vC;
    acc += cfD * vD;
  }
  acc += __shfl_xor(acc, 32, 64);
  if (h == 0) xagg16[n*32 + c] = f2bf(acc * inv);
}

// ---- AB2: gout via MFMA into LDS, then P16 via MFMA. Split each 16-node
// tile across 2 blocks (col halves): 750 blocks -> ~2.9/CU occupancy (was
// 1.47, R13 counters) so phase C's load chain is latency-hidden. Phase B
// (8 MFMA) duplicated per half — trivial. Bit-identical output. ----
__global__ void __launch_bounds__(256) k_ab2(
    const unsigned short* __restrict__ xagg16, const unsigned short* __restrict__ gwT16,
    const float* __restrict__ gat_b, const unsigned short* __restrict__ Bt16,
    unsigned short* __restrict__ P16){
  __shared__ unsigned short go[16*520];
  int t = threadIdx.x, w = t>>6, lane = t&63;
  int tile = blockIdx.x >> 1, half = blockIdx.x & 1;
  int n0 = tile*16;
  int r = lane & 15, kq = (lane >> 4) * 8;
  // ---- Phase B: rows 0-15 x cols [w*128, w*128+128) = 8 MFMA (16x16, K=32) ----
  {
    frag8 a = *(const frag8*)&xagg16[(size_t)(n0 + r)*32 + kq];   // reused 8x
    int rowb = (lane >> 4) * 4;
    #pragma unroll
    for (int m = 0; m < 8; m++){
      int c0 = w*128 + m*16;
      frag8 b = *(const frag8*)&gwT16[(size_t)(c0 + r)*32 + kq];
      f32x4 c4 = {0,0,0,0};
      c4 = __builtin_amdgcn_mfma_f32_16x16x32_bf16(a, b, c4, 0, 0, 0);
      float bb = gat_b[c0 + r];          // D col = lane&15 = r
      #pragma unroll
      for (int i=0;i<4;i++)
        go[(rowb+i)*520 + c0 + r] = f2bf(fmaxf(c4[i] + bb, 0.f));
    }
  }
  __syncthreads();
  // ---- Phase C: wave w -> cols [half*128 + w*32, +32): 2 accumulators ----
  {
    const unsigned short* arow  = go + r*520 + kq;
    const unsigned short* bbase = Bt16 + (size_t)(half*128 + w*32 + r)*512 + kq;
    f32x4 acc0 = {0,0,0,0}, acc1 = {0,0,0,0};
    for (int k = 0; k < 512; k += 32){
      frag8 a  = *(const frag8*)(arow + k);
      frag8 b0 = *(const frag8*)(bbase + k);
      frag8 b1 = *(const frag8*)(bbase + 16*512 + k);
      acc0 = __builtin_amdgcn_mfma_f32_16x16x32_bf16(a, b0, acc0, 0, 0, 0);
      acc1 = __builtin_amdgcn_mfma_f32_16x16x32_bf16(a, b1, acc1, 0, 0, 0);
    }
    int rowb = n0 + (lane >> 4)*4;
    int col  = half*128 + w*32 + r;
    #pragma unroll
    for (int i=0;i<4;i++){
      P16[(size_t)(rowb+i)*256 + col     ] = f2bf(acc0[i]);
      P16[(size_t)(rowb+i)*256 + col + 16] = f2bf(acc1[i]);
    }
  }
}

// per-edge MLP head: 16 lanes/edge, bf16 P loads
__global__ void k_edge(const int* __restrict__ ei, const unsigned short* __restrict__ P16,
                       const float* __restrict__ b1,
                       const float* __restrict__ w2, const float* __restrict__ b2,
                       float* __restrict__ out){
  int e = blockIdx.x*16 + (threadIdx.x >> 4);
  int l = threadIdx.x & 15;            // lane covers channels [l*8, l*8+8)
  if (e >= EE) return;
  int s = ei[e], d = ei[EE+e];
  const u16x8 Av = *(const u16x8*)&P16[(size_t)s*256 + l*8];
  const u16x8 Bv = *(const u16x8*)&P16[(size_t)d*256 + 128 + l*8];
  const float4 b1a = *(const float4*)&b1[l*8];
  const float4 b1b = *(const float4*)&b1[l*8+4];
  const float4 w2a = *(const float4*)&w2[l*8];
  const float4 w2b = *(const float4*)&w2[l*8+4];
  float h0 = fmaxf(bf2f(Av[0])+bf2f(Bv[0])+b1a.x, 0.f);
  float h1 = fmaxf(bf2f(Av[1])+bf2f(Bv[1])+b1a.y, 0.f);
  float h2 = fmaxf(bf2f(Av[2])+bf2f(Bv[2])+b1a.z, 0.f);
  float h3 = fmaxf(bf2f(Av[3])+bf2f(Bv[3])+b1a.w, 0.f);
  float h4 = fmaxf(bf2f(Av[4])+bf2f(Bv[4])+b1b.x, 0.f);
  float h5 = fmaxf(bf2f(Av[5])+bf2f(Bv[5])+b1b.y, 0.f);
  float h6 = fmaxf(bf2f(Av[6])+bf2f(Bv[6])+b1b.z, 0.f);
  float h7 = fmaxf(bf2f(Av[7])+bf2f(Bv[7])+b1b.w, 0.f);
  float acc = h0*w2a.x + h1*w2a.y + h2*w2a.z + h3*w2a.w
            + h4*w2b.x + h5*w2b.y + h6*w2b.z + h7*w2b.w;
  #pragma unroll
  for (int m=8;m>0;m>>=1) acc += __shfl_xor(acc,m,64);
  if (l==0) out[e] = 1.f/(1.f + expf(-(acc + b2[0])));
}

extern "C" void kernel_launch(void* const* d_in, const int* in_sizes, int n_in,
                              void* d_out, int out_size, void* d_ws, size_t ws_size,
                              hipStream_t stream){
  const float* basis0 = (const float*)d_in[0];
  const float* comp0  = (const float*)d_in[1];
  const float* root0  = (const float*)d_in[2];
  const float* rbias0 = (const float*)d_in[3];
  const float* basis1 = (const float*)d_in[4];
  const float* comp1  = (const float*)d_in[5];
  const float* root1  = (const float*)d_in[6];
  const float* rbias1 = (const float*)d_in[7];
  const float* basis2 = (const float*)d_in[8];
  const float* comp2  = (const float*)d_in[9];
  const float* root2  = (const float*)d_in[10];
  const float* rbias2 = (const float*)d_in[11];
  const float* basis3 = (const float*)d_in[12];
  const float* comp3  = (const float*)d_in[13];
  const float* root3  = (const float*)d_in[14];
  const float* rbias3 = (const float*)d_in[15];
  const float* gat_w = (const float*)d_in[16];
  const float* a_src = (const float*)d_in[17];
  const float* a_dst = (const float*)d_in[18];
  const float* gat_b = (const float*)d_in[19];
  const float* w1 = (const float*)d_in[20];
  const float* b1 = (const float*)d_in[21];
  const float* w2 = (const float*)d_in[22];
  const float* b2 = (const float*)d_in[23];
  const int* ei = (const int*)d_in[24];
  const int* et = (const int*)d_in[25];
  float* out = (float*)d_out;

  // workspace carve-up (16B-aligned sections)
  float* p = (float*)d_ws;
  int* cursor = (int*)p; p += NN;              // doubles as degree after k_pdc
  int* pks    = (int*)p; p += NN*CAP;          // bucket CSR (64 slots/node)
  unsigned short* W016 = (unsigned short*)p; p += NN*32;       // 2*NN*32 bf16
  float* Wcat = p; p += 24576;
  unsigned short* Bt16 = (unsigned short*)p; p += 256*512/2;
  unsigned short* H16a = (unsigned short*)p; p += NN*96;       // NN*192 bf16
  unsigned short* H16b = (unsigned short*)p; p += NN*96;       // NN*192 bf16
  unsigned short* X4   = (unsigned short*)p; p += NN*16;       // NN*32 bf16
  float* gwa  = p; p += 64;                    // gw@a_src (32) + gw@a_dst (32)
  unsigned short* gwT16 = (unsigned short*)p; p += 512*32/2;   // gw^T bf16 [512][32]
  float* asv  = p; p += NN;
  float* adv  = p; p += NN;
  unsigned short* xagg16 = (unsigned short*)p; p += NN*16;     // NN*32 bf16
  unsigned short* P16 = (unsigned short*)p; p += NN*128;       // NN*256 bf16

  auto grid = [](long long n){ return dim3((unsigned)((n + 255)/256)); };

  // ---- zero cursor only, then single fused prep kernel ----
  hipMemsetAsync(cursor, 0, (size_t)NN*sizeof(int), stream);
  k_pdc<<<grid(2LL*NN*32 + 24576 + 256*512 + 64*64 + 512*32),256,0,stream>>>(
        ei, et, cursor, pks,
        basis0, comp0, basis1,comp1,root1, basis2,comp2,root2,
        basis3,comp3,root3, w1, gat_w, a_src, a_dst, W016, Wcat, Bt16, gwa, gwT16);

  // ---- RGCN stack: wave-per-node gathers; 8 nodes/block (R11 config) ----
  k_f1<<<dim3(NN/8),512,0,stream>>>(W016, root0, rbias0, cursor, pks, Wcat, H16a);
  k_f2<<<dim3(NN/8),512,0,stream>>>(H16a, rbias1, cursor, pks, Wcat + 6144, H16b);
  k_f3<<<dim3(NN/8),512,0,stream>>>(H16b, rbias2, cursor, pks, Wcat + 18432, H16a);
  k_f4<<<dim3(NN/4),256,0,stream>>>(H16a, rbias3, cursor, pks, gwa, X4, asv, adv);

  // ---- GAT softmax+aggregate (bf16 out) then dual-MFMA transform ----
  k_gs2<<<dim3(NN/4),256,0,stream>>>(cursor, pks, asv, adv, X4, xagg16);
  k_ab2<<<dim3((NN/16)*2),256,0,stream>>>(xagg16, gwT16, gat_b, Bt16, P16);

  // ---- per-edge head ----
  k_edge<<<dim3((EE+15)/16),256,0,stream>>>(ei, P16, b1, w2, b2, out);
}